// Round 9
// baseline (39517.282 us; speedup 1.0000x reference)
//
#include <hip/hip_runtime.h>
#include <hip/hip_bf16.h>

// IEBins forward. Round 9: zrx at NACC=8 (was 4) — 48 f32-FMA per 2 loads
// (was 24). Round 8 showed zrx latency-bound again (VALUBusy 47%): f32
// halved VALU work per load vs f64 but kept the same load stream. Masters
// stay f64 (f32 masters would put logit error ~the reference's own band ->
// real iter-0 flip risk). Accumulation order identical to round 8 ->
// bit-identical output (absmax 1.0).
// Known remaining inefficiency (next round if needed): tap-outer loop
// re-streams activations 5x; co-resident acts+weights (6.8 MB) > 4 MiB
// XCD L2 -> FETCH 380 MB vs 88 ideal.

#define HD  128
#define CDC 192
#define BN  16
#define OCH 256
#define GC  576
#define NB  2
#define HH  120
#define WW  160
#define HW  (HH*WW)
#define BHW (NB*HW)
#define PXT (BHW/128)          // 300 pixel tiles of 128 px
#define GXP (((PXT+7)/8)*8)    // 304 padded
#define TPX (GXP/8)            // 38 tiles per XCD slab

// ---------------------------------------------------------------- init ----
__global__ __launch_bounds__(256) void k_init(const float* __restrict__ gh,
        float* __restrict__ h, double* __restrict__ edges, double* __restrict__ cd){
  const int i = blockIdx.x*256 + threadIdx.x;
  const int nh = NB*HD*HW;
  if (i < nh) h[i] = gh[i];
  if (i < BHW){
    const int b = i / HW, r = i - b*HW;
    double e = 0.0;
    #pragma unroll
    for (int k=0;k<BN;++k){
      edges[(b*(BN+1)+k)*HW + r] = e;
      cd[(b*BN+k)*HW + r] = e + 2.5;
      e += 5.0;
    }
    edges[(b*(BN+1)+BN)*HW + r] = e;   // 80
  }
}

// ------------------------------------------------- weight transpose ------
__global__ __launch_bounds__(256) void k_wxpose(const float* __restrict__ w,
        float* __restrict__ wt, const int Cout, const int CIN, const int TAPS,
        const int n){
  const int i = blockIdx.x*256 + threadIdx.x;
  if (i >= n) return;
  const int ct = CIN*TAPS;
  const int o = i / ct;
  const int rem = i - o*ct;
  const int c = rem / TAPS;
  const int t = rem - c*TAPS;
  wt[((size_t)c*TAPS + t)*Cout + o] = w[i];
}

// ------------------------------------------- XCD-aware block decode ------
template<int GY>
__device__ __forceinline__ bool blk_decode(int& xs, int& yg){
  const int id  = blockIdx.x;
  const int xcd = id & 7;
  const int s   = id >> 3;
  yg = s & (GY-1);
  const int k = s / GY;
  xs = xcd*TPX + k;
  return xs < PXT;
}

// ----------------------------------------------- fast generic conv -------
template<typename TI,int CIN,int KH,int KW,int NACC,int GY,int ACT>
__global__ __launch_bounds__(256) void k_fconv(
    const TI* __restrict__ in, const float* __restrict__ wt,
    const float* __restrict__ bias, float* __restrict__ out, const int Cout){
  int xs, yg;
  if (!blk_decode<GY>(xs, yg)) return;
  const int lane = threadIdx.x & 63;
  const int wvu  = __builtin_amdgcn_readfirstlane((int)(threadIdx.x >> 6));
  const int ow0  = (yg*4 + wvu)*NACC;
  const int pb   = xs*128;
  const int b    = pb / HW;
  int rr[2], yy[2], xx[2];
  #pragma unroll
  for (int i=0;i<2;++i){
    const int r = pb + i*64 + lane - b*HW;
    rr[i]=r; yy[i]=r/WW; xx[i]=r - (r/WW)*WW;
  }
  double acc[2][NACC];
  #pragma unroll
  for (int j=0;j<NACC;++j){
    const double bj = (double)bias[ow0+j];
    #pragma unroll
    for (int i=0;i<2;++i) acc[i][j]=bj;
  }
  const TI* inb = in + (size_t)b*CIN*HW;
  const int TAPS = KH*KW;
  const int CH = (CIN < 32) ? CIN : 32;
  int dy = -(KH/2), dx = -(KW/2);
  #pragma unroll 1
  for (int t=0;t<TAPS;++t){
    int po[2]; bool va[2];
    #pragma unroll
    for (int i=0;i<2;++i){
      const int iy = yy[i]+dy, ix = xx[i]+dx;
      va[i] = ((unsigned)iy < (unsigned)HH) && ((unsigned)ix < (unsigned)WW);
      po[i] = va[i] ? iy*WW+ix : 0;
    }
    #pragma unroll 1
    for (int c0=0;c0<CIN;c0+=CH){
      float ca[2][NACC];
      #pragma unroll
      for (int j=0;j<NACC;++j)
        #pragma unroll
        for (int i=0;i<2;++i) ca[i][j]=0.f;
      const float* wr = wt + ((size_t)c0*TAPS + t)*Cout + ow0;
      #pragma unroll 8
      for (int c=0;c<CH;++c){
        float v[2];
        const size_t cc = (size_t)(c0+c)*HW;
        #pragma unroll
        for (int i=0;i<2;++i) v[i] = va[i] ? (float)inb[cc + po[i]] : 0.f;
        #pragma unroll
        for (int j=0;j<NACC;++j){
          const float wj = wr[j];
          #pragma unroll
          for (int i=0;i<2;++i) ca[i][j] = fmaf(v[i], wj, ca[i][j]);
        }
        wr += (size_t)TAPS*Cout;
      }
      #pragma unroll
      for (int j=0;j<NACC;++j)
        #pragma unroll
        for (int i=0;i<2;++i) acc[i][j] += (double)ca[i][j];
    }
    if (++dx > KW/2){ dx = -(KW/2); ++dy; }
  }
  #pragma unroll
  for (int j=0;j<NACC;++j)
    #pragma unroll
    for (int i=0;i<2;++i){
      double v = acc[i][j];
      if (ACT==1) v = v > 0.0 ? v : 0.0;
      out[((size_t)b*Cout + ow0 + j)*HW + rr[i]] = (float)v;
    }
}

// -------------------------------------------- GRU chunked segments -------
// Two-gate (z,r) chunked accumulate. unroll 4 (cap held loads at NACC=8).
template<int C,int NACC>
__device__ __forceinline__ void fseg2c(const float* __restrict__ base,
    const int po[2], const bool va[2],
    const float* __restrict__ wz0, const float* __restrict__ wr0,
    double az[2][NACC], double ar[2][NACC]){
  #pragma unroll 1
  for (int c0=0;c0<C;c0+=32){
    float cz[2][NACC], cr[2][NACC];
    #pragma unroll
    for (int j=0;j<NACC;++j)
      #pragma unroll
      for (int i=0;i<2;++i){ cz[i][j]=0.f; cr[i][j]=0.f; }
    const float* wz = wz0 + (size_t)c0*5*HD;
    const float* wr = wr0 + (size_t)c0*5*HD;
    #pragma unroll 4
    for (int c=0;c<32;++c){
      float v[2];
      const size_t cc = (size_t)(c0+c)*HW;
      #pragma unroll
      for (int i=0;i<2;++i) v[i] = va[i] ? base[cc + po[i]] : 0.f;
      #pragma unroll
      for (int j=0;j<NACC;++j){
        const float wzj = wz[j], wrj = wr[j];
        #pragma unroll
        for (int i=0;i<2;++i){
          cz[i][j] = fmaf(v[i], wzj, cz[i][j]);
          cr[i][j] = fmaf(v[i], wrj, cr[i][j]);
        }
      }
      wz += 5*HD; wr += 5*HD;
    }
    #pragma unroll
    for (int j=0;j<NACC;++j)
      #pragma unroll
      for (int i=0;i<2;++i){ az[i][j]+=(double)cz[i][j]; ar[i][j]+=(double)cr[i][j]; }
  }
}
// Three-gate (z,r,qx) chunked accumulate — 3*NACC*2 FMA per 2 loads.
template<int C,int NACC>
__device__ __forceinline__ void fseg3c(const float* __restrict__ base,
    const int po[2], const bool va[2],
    const float* __restrict__ wz0, const float* __restrict__ wr0,
    const float* __restrict__ wq0,
    double az[2][NACC], double ar[2][NACC], double aq[2][NACC]){
  #pragma unroll 1
  for (int c0=0;c0<C;c0+=32){
    float cz[2][NACC], cr[2][NACC], cq[2][NACC];
    #pragma unroll
    for (int j=0;j<NACC;++j)
      #pragma unroll
      for (int i=0;i<2;++i){ cz[i][j]=0.f; cr[i][j]=0.f; cq[i][j]=0.f; }
    const float* wz = wz0 + (size_t)c0*5*HD;
    const float* wr = wr0 + (size_t)c0*5*HD;
    const float* wq = wq0 + (size_t)c0*5*HD;
    #pragma unroll 4
    for (int c=0;c<32;++c){
      float v[2];
      const size_t cc = (size_t)(c0+c)*HW;
      #pragma unroll
      for (int i=0;i<2;++i) v[i] = va[i] ? base[cc + po[i]] : 0.f;
      #pragma unroll
      for (int j=0;j<NACC;++j){
        const float wzj = wz[j], wrj = wr[j], wqj = wq[j];
        #pragma unroll
        for (int i=0;i<2;++i){
          cz[i][j] = fmaf(v[i], wzj, cz[i][j]);
          cr[i][j] = fmaf(v[i], wrj, cr[i][j]);
          cq[i][j] = fmaf(v[i], wqj, cq[i][j]);
        }
      }
      wz += 5*HD; wr += 5*HD; wq += 5*HD;
    }
    #pragma unroll
    for (int j=0;j<NACC;++j)
      #pragma unroll
      for (int i=0;i<2;++i){
        az[i][j]+=(double)cz[i][j]; ar[i][j]+=(double)cr[i][j]; aq[i][j]+=(double)cq[i][j];
      }
  }
}
// One-gate chunked accumulate.
template<int C,int NACC>
__device__ __forceinline__ void fseg1c(const float* __restrict__ base,
    const int po[2], const bool va[2], const float* __restrict__ wq0,
    double aq[2][NACC]){
  #pragma unroll 1
  for (int c0=0;c0<C;c0+=32){
    float cq[2][NACC];
    #pragma unroll
    for (int j=0;j<NACC;++j)
      #pragma unroll
      for (int i=0;i<2;++i) cq[i][j]=0.f;
    const float* wq = wq0 + (size_t)c0*5*HD;
    #pragma unroll 8
    for (int c=0;c<32;++c){
      float v[2];
      const size_t cc = (size_t)(c0+c)*HW;
      #pragma unroll
      for (int i=0;i<2;++i) v[i] = va[i] ? base[cc + po[i]] : 0.f;
      #pragma unroll
      for (int j=0;j<NACC;++j){
        const float wj = wq[j];
        #pragma unroll
        for (int i=0;i<2;++i) cq[i][j] = fmaf(v[i], wj, cq[i][j]);
      }
      wq += 5*HD;
    }
    #pragma unroll
    for (int j=0;j<NACC;++j)
      #pragma unroll
      for (int i=0;i<2;++i) aq[i][j]+=(double)cq[i][j];
  }
}

// Fused z,r,qx. NACC=8, GY=4 (48 f32-FMA per 2 loads).
template<int VERT>
__global__ __launch_bounds__(256) void k_fgru_zrx(
    const float* __restrict__ h, const float* __restrict__ d4,
    const float* __restrict__ ctx,
    const float* __restrict__ wtz, const float* __restrict__ wtr,
    const float* __restrict__ wtq,
    const float* __restrict__ bz, const float* __restrict__ br,
    const float* __restrict__ bq,
    float* __restrict__ zg, float* __restrict__ rgh, float* __restrict__ qx){
  const int NACC = 8;
  int xs, yg;
  if (!blk_decode<4>(xs, yg)) return;
  const int lane = threadIdx.x & 63;
  const int wvu  = __builtin_amdgcn_readfirstlane((int)(threadIdx.x >> 6));
  const int ow0  = (yg*4 + wvu)*NACC;       // 0..127
  const int pb   = xs*128;
  const int b    = pb / HW;
  int rr[2], yy[2], xx[2];
  #pragma unroll
  for (int i=0;i<2;++i){
    const int r = pb + i*64 + lane - b*HW;
    rr[i]=r; yy[i]=r/WW; xx[i]=r - (r/WW)*WW;
  }
  double az[2][NACC], ar[2][NACC], aq[2][NACC];
  #pragma unroll
  for (int j=0;j<NACC;++j){
    const double bzj=(double)bz[ow0+j], brj=(double)br[ow0+j], bqj=(double)bq[ow0+j];
    #pragma unroll
    for (int i=0;i<2;++i){ az[i][j]=bzj; ar[i][j]=brj; aq[i][j]=bqj; }
  }
  const float* ab = h  + (size_t)b*HD *HW;
  const float* db = d4 + (size_t)b*OCH*HW;
  const float* cb = ctx+ (size_t)b*CDC*HW;
  #pragma unroll 1
  for (int t=0;t<5;++t){
    const int dy = VERT ? (t-2) : 0;
    const int dx = VERT ? 0 : (t-2);
    int po[2]; bool va[2];
    #pragma unroll
    for (int i=0;i<2;++i){
      const int iy = yy[i]+dy, ix = xx[i]+dx;
      va[i] = ((unsigned)iy < (unsigned)HH) && ((unsigned)ix < (unsigned)WW);
      po[i] = va[i] ? iy*WW+ix : 0;
    }
    fseg2c<HD ,NACC>(ab, po, va,
        wtz + ((size_t)0*5 + t)*HD + ow0,  wtr + ((size_t)0*5 + t)*HD + ow0, az, ar);
    fseg3c<OCH,NACC>(db, po, va,
        wtz + ((size_t)HD*5 + t)*HD + ow0, wtr + ((size_t)HD*5 + t)*HD + ow0,
        wtq + ((size_t)HD*5 + t)*HD + ow0, az, ar, aq);
    fseg3c<CDC,NACC>(cb, po, va,
        wtz + ((size_t)(HD+OCH)*5 + t)*HD + ow0, wtr + ((size_t)(HD+OCH)*5 + t)*HD + ow0,
        wtq + ((size_t)(HD+OCH)*5 + t)*HD + ow0, az, ar, aq);
  }
  #pragma unroll
  for (int j=0;j<NACC;++j)
    #pragma unroll
    for (int i=0;i<2;++i){
      const size_t oi = ((size_t)b*HD + ow0 + j)*HW + rr[i];
      zg[oi]  = (float)(1.0/(1.0+exp(-az[i][j])));
      rgh[oi] = (float)((1.0/(1.0+exp(-ar[i][j]))) * (double)h[oi]);
      qx[oi]  = (float)aq[i][j];
    }
}

// q over rgh channels (128) + in-place hidden update. NACC=8, GY=4.
template<int VERT>
__global__ __launch_bounds__(256) void k_fgru_qh(
    const float* __restrict__ rgh, const float* __restrict__ wtq,
    const float* __restrict__ qx, const float* __restrict__ zg,
    float* __restrict__ h){
  const int NACC = 8;
  int xs, yg;
  if (!blk_decode<4>(xs, yg)) return;
  const int lane = threadIdx.x & 63;
  const int wvu  = __builtin_amdgcn_readfirstlane((int)(threadIdx.x >> 6));
  const int ow0  = (yg*4 + wvu)*NACC;
  const int pb   = xs*128;
  const int b    = pb / HW;
  int rr[2], yy[2], xx[2];
  #pragma unroll
  for (int i=0;i<2;++i){
    const int r = pb + i*64 + lane - b*HW;
    rr[i]=r; yy[i]=r/WW; xx[i]=r - (r/WW)*WW;
  }
  double aq[2][NACC];
  #pragma unroll
  for (int j=0;j<NACC;++j)
    #pragma unroll
    for (int i=0;i<2;++i)
      aq[i][j] = (double)qx[((size_t)b*HD + ow0 + j)*HW + rr[i]];
  const float* gb = rgh + (size_t)b*HD*HW;
  #pragma unroll 1
  for (int t=0;t<5;++t){
    const int dy = VERT ? (t-2) : 0;
    const int dx = VERT ? 0 : (t-2);
    int po[2]; bool va[2];
    #pragma unroll
    for (int i=0;i<2;++i){
      const int iy = yy[i]+dy, ix = xx[i]+dx;
      va[i] = ((unsigned)iy < (unsigned)HH) && ((unsigned)ix < (unsigned)WW);
      po[i] = va[i] ? iy*WW+ix : 0;
    }
    fseg1c<HD,NACC>(gb, po, va, wtq + ((size_t)0*5 + t)*HD + ow0, aq);
  }
  #pragma unroll
  for (int j=0;j<NACC;++j)
    #pragma unroll
    for (int i=0;i<2;++i){
      const size_t oi = ((size_t)b*HD + ow0 + j)*HW + rr[i];
      const double z = (double)zg[oi];
      h[oi] = (float)((1.0-z)*(double)h[oi] + z*tanh(aq[i][j]));
    }
}

// ------------------- softmax + depth_r + unc + label + cs + bin update ----
__global__ __launch_bounds__(256) void k_stats(const float* __restrict__ lg,
    double* __restrict__ edges, double* __restrict__ cd, float* __restrict__ out,
    const int it){
  const int px = blockIdx.x*256 + threadIdx.x;
  const int b = px / HW, r = px - b*HW;
  double l[BN], p[BN], c[BN];
  double m = -1e300;
  #pragma unroll
  for (int k=0;k<BN;++k){ l[k] = (double)lg[(b*BN+k)*HW + r]; m = l[k]>m?l[k]:m; }
  double s = 0.0;
  #pragma unroll
  for (int k=0;k<BN;++k){ p[k] = exp(l[k]-m); s += p[k]; }
  double dr = 0.0;
  #pragma unroll
  for (int k=0;k<BN;++k){ c[k] = cd[(b*BN+k)*HW + r]; p[k] = p[k]/s; dr += p[k]*c[k]; }
  double var = 0.0;
  #pragma unroll
  for (int k=0;k<BN;++k){ const double d = c[k]-dr; var += p[k]*(d*d); }
  const double un = sqrt(var);
  int cnt = 0;
  #pragma unroll
  for (int k=1;k<BN;++k) cnt += (dr >= edges[(b*(BN+1)+k)*HW + r]) ? 1 : 0;
  const double etop = edges[(b*(BN+1)+BN)*HW + r];
  const int label = (dr >= etop) ? 0 : cnt;
  double csv = c[0];
  #pragma unroll
  for (int k=1;k<BN;++k) csv = (label==k) ? c[k] : csv;
  out[((0*6+it)*NB + b)*HW + r] = (float)dr;
  out[((1*6+it)*NB + b)*HW + r] = (float)csv;
  out[((2*6+it)*NB + b)*HW + r] = (float)un;
  const double start = dr - 0.5*un > 0.0 ? dr - 0.5*un : 0.0;
  const double step = un * (1.0/BN);
  double e = start;
  double prev = e < 0.0 ? 0.0 : (e > 80.0 ? 80.0 : e);
  edges[(b*(BN+1)+0)*HW + r] = prev;
  #pragma unroll
  for (int k=1;k<=BN;++k){
    e = e + step;
    const double ec = e < 0.0 ? 0.0 : (e > 80.0 ? 80.0 : e);
    edges[(b*(BN+1)+k)*HW + r] = ec;
    cd[(b*BN + (k-1))*HW + r] = 0.5*(prev + ec);
    prev = ec;
  }
}

// ----------------------------------------------------------- launcher ----
extern "C" void kernel_launch(void* const* d_in, const int* in_sizes, int n_in,
                              void* d_out, int out_size, void* d_ws, size_t ws_size,
                              hipStream_t stream){
  const float* ctx = (const float*)d_in[1];
  const float* gh  = (const float*)d_in[2];
  const float *e1w=(const float*)d_in[3],  *e1b=(const float*)d_in[4];
  const float *e2w=(const float*)d_in[5],  *e2b=(const float*)d_in[6];
  const float *e3w=(const float*)d_in[7],  *e3b=(const float*)d_in[8];
  const float *e4w=(const float*)d_in[9],  *e4b=(const float*)d_in[10];
  const float *z1w=(const float*)d_in[11], *z1b=(const float*)d_in[12];
  const float *r1w=(const float*)d_in[13], *r1b=(const float*)d_in[14];
  const float *q1w=(const float*)d_in[15], *q1b=(const float*)d_in[16];
  const float *z2w=(const float*)d_in[17], *z2b=(const float*)d_in[18];
  const float *r2w=(const float*)d_in[19], *r2b=(const float*)d_in[20];
  const float *q2w=(const float*)d_in[21], *q2b=(const float*)d_in[22];
  const float *p1w=(const float*)d_in[23], *p1b=(const float*)d_in[24];
  const float *p2w=(const float*)d_in[25], *p2b=(const float*)d_in[26];
  float* out = (float*)d_out;

  // doubles first (alignment), then floats
  double* edges = (double*)d_ws;                       // NB*17*HW
  double* cd    = edges + (size_t)NB*(BN+1)*HW;        // NB*16*HW
  float*  fb    = (float*)(cd + (size_t)NB*BN*HW);
  float* h    = fb;                                    // NB*128*HW
  float* d4   = h    + (size_t)NB*HD*HW;               // NB*256*HW
  float* bufA = d4   + (size_t)NB*OCH*HW;              // zg
  float* bufB = bufA + (size_t)NB*HD*HW;               // rgh
  float* bufC = bufB + (size_t)NB*HD*HW;               // qx
  float* lgts = bufC + (size_t)NB*HD*HW;               // NB*16*HW
  float* wp   = lgts + (size_t)NB*BN*HW;
  float* we1 = wp;              wp += (size_t)HD*16*49;
  float* we2 = wp;              wp += (size_t)HD*HD*9;
  float* we3 = wp;              wp += (size_t)HD*HD*9;
  float* we4 = wp;              wp += (size_t)OCH*HD*9;
  float* wz1 = wp;              wp += (size_t)HD*GC*5;
  float* wr1 = wp;              wp += (size_t)HD*GC*5;
  float* wq1 = wp;              wp += (size_t)HD*GC*5;
  float* wz2 = wp;              wp += (size_t)HD*GC*5;
  float* wr2 = wp;              wp += (size_t)HD*GC*5;
  float* wq2 = wp;              wp += (size_t)HD*GC*5;
  float* wp1 = wp;              wp += (size_t)HD*HD*9;
  float* wp2 = wp;              wp += (size_t)16*HD*9;

  const dim3 blk(256);

  #define XP(src,dst,Cout_,CIN_,TAPS_) { const int n=(Cout_)*(CIN_)*(TAPS_); \
    k_wxpose<<<dim3((n+255)/256), blk, 0, stream>>>(src, dst, Cout_, CIN_, TAPS_, n); }
  XP(e1w, we1, HD, 16, 49); XP(e2w, we2, HD, HD, 9); XP(e3w, we3, HD, HD, 9);
  XP(e4w, we4, OCH, HD, 9);
  XP(z1w, wz1, HD, GC, 5); XP(r1w, wr1, HD, GC, 5); XP(q1w, wq1, HD, GC, 5);
  XP(z2w, wz2, HD, GC, 5); XP(r2w, wr2, HD, GC, 5); XP(q2w, wq2, HD, GC, 5);
  XP(p1w, wp1, HD, HD, 9); XP(p2w, wp2, 16, HD, 9);
  #undef XP

  k_init<<<dim3((NB*HD*HW+255)/256), blk, 0, stream>>>(gh, h, edges, cd);

  const int G8 = GXP*8, G4 = GXP*4, G1 = GXP;
  const int PXB = BHW/256;

  for (int it=0; it<6; ++it){
    // encoder (e1 reads f64 cd)
    k_fconv<double,16 ,7,7,8,4,1><<<dim3(G4), blk, 0, stream>>>(cd,   we1, e1b, bufA, HD);
    k_fconv<float ,128,3,3,8,4,1><<<dim3(G4), blk, 0, stream>>>(bufA, we2, e2b, bufB, HD);
    k_fconv<float ,128,3,3,8,4,1><<<dim3(G4), blk, 0, stream>>>(bufB, we3, e3b, bufA, HD);
    k_fconv<float ,128,3,3,8,8,1><<<dim3(G8), blk, 0, stream>>>(bufA, we4, e4b, d4,  OCH);
    // horizontal GRU: fused z+r+qx (NACC=8), then q_h + hidden update
    k_fgru_zrx<0><<<dim3(G4), blk, 0, stream>>>(h, d4, ctx, wz1, wr1, wq1,
                                                z1b, r1b, q1b, bufA, bufB, bufC);
    k_fgru_qh <0><<<dim3(G4), blk, 0, stream>>>(bufB, wq1, bufC, bufA, h);
    // vertical GRU
    k_fgru_zrx<1><<<dim3(G4), blk, 0, stream>>>(h, d4, ctx, wz2, wr2, wq2,
                                                z2b, r2b, q2b, bufA, bufB, bufC);
    k_fgru_qh <1><<<dim3(G4), blk, 0, stream>>>(bufB, wq2, bufC, bufA, h);
    // PHead
    k_fconv<float,128,3,3,8,4,1><<<dim3(G4), blk, 0, stream>>>(h,    wp1, p1b, bufA, HD);
    k_fconv<float,128,3,3,4,1,0><<<dim3(G1), blk, 0, stream>>>(bufA, wp2, p2b, lgts, 16);
    k_stats<<<dim3(PXB), blk, 0, stream>>>(lgts, edges, cd, out, it);
  }
}

// Round 11
// 27916.141 us; speedup vs baseline: 1.4156x; 1.4156x over previous
//
#include <hip/hip_runtime.h>
#include <hip/hip_bf16.h>

// IEBins forward. Round 11: r10's memory structure + r9's EXACT arithmetic.
// r10 failed (absmax 6.75 = a dr>=edges[16] label flip): the tap-inner
// accumulation reorder resampled ~1e-6-scale rounding at knife-edge pixels.
// Rule going forward: accumulation order (r9's: tap-outer, seg order
// H,d4,ctx, chunk-32 f32 partials -> f64 masters, channels ascending) is
// FROZEN — it passed twice (r8, r9) at absmax 1.0.
// Kept from r10 (value-preserving only):
//   - zero-halo padded planes (168x126): OOB load = 0.0f, exactly what
//     r9's cndmask produced -> no va/cndmask/po-select per load.
//   - lane owns 2 adjacent px: p[0],p[1] unconditional loads (compiler can
//     merge to dwordx2), shared base address.
//   - contiguous-slab XCD swizzle.

#define HD  128
#define CDC 192
#define BN  16
#define OCH 256
#define GC  576
#define NB  2
#define HH  120
#define WW  160
#define HW  (HH*WW)
#define BHW (NB*HW)
#define PXT (BHW/128)          // 300 pixel tiles of 128 px
#define GXP (((PXT+7)/8)*8)    // 304 padded
#define TPX (GXP/8)            // 38 tiles per XCD slab
// padded plane geometry: 3 halo rows top/bottom, 4 cols left/right
#define PWW 168
#define PHH 126
#define PHW (PWW*PHH)          // 21168
#define POFF(y,x) (((y)+3)*PWW + (x) + 4)

__device__ __forceinline__ float2 ldf2(const float* p){ return *(const float2*)p; }
__device__ __forceinline__ void stf2(float* p, float a, float b){
  *(float2*)p = make_float2(a,b);
}

// ---------------------------------------------------------------- zero ----
__global__ __launch_bounds__(256) void k_zero32(float* __restrict__ p, const size_t n){
  const size_t i = (size_t)blockIdx.x*256 + threadIdx.x;
  for (size_t k=i; k<n; k += (size_t)gridDim.x*256) p[k] = 0.f;
}
__global__ __launch_bounds__(256) void k_zero64(double* __restrict__ p, const size_t n){
  const size_t i = (size_t)blockIdx.x*256 + threadIdx.x;
  for (size_t k=i; k<n; k += (size_t)gridDim.x*256) p[k] = 0.0;
}

// ------------------------------------------------------------- pad ctx ----
__global__ __launch_bounds__(256) void k_pad(const float* __restrict__ src,
        float* __restrict__ dst, const int nplanes){
  const int i = blockIdx.x*256 + threadIdx.x;
  if (i >= nplanes*HW) return;
  const int bc = i / HW, r = i - bc*HW;
  const int y = r / WW, x = r - y*WW;
  dst[(size_t)bc*PHW + POFF(y,x)] = src[i];
}

// ---------------------------------------------------------------- init ----
__global__ __launch_bounds__(256) void k_init(const float* __restrict__ gh,
        float* __restrict__ h, double* __restrict__ edges, double* __restrict__ cdp){
  const int i = blockIdx.x*256 + threadIdx.x;
  const int nh = NB*HD*HW;
  if (i < nh){
    const int bc = i / HW, r = i - bc*HW;
    const int y = r / WW, x = r - y*WW;
    h[(size_t)bc*PHW + POFF(y,x)] = gh[i];
  }
  if (i < BHW){
    const int b = i / HW, r = i - b*HW;
    const int y = r / WW, x = r - y*WW;
    const int pr = POFF(y,x);
    double e = 0.0;
    #pragma unroll
    for (int k=0;k<BN;++k){
      edges[(b*(BN+1)+k)*HW + r] = e;
      cdp[((size_t)b*BN+k)*PHW + pr] = e + 2.5;
      e += 5.0;
    }
    edges[(b*(BN+1)+BN)*HW + r] = e;   // 80
  }
}

// ------------------------------------------------- weight transpose ------
// w[o][c][tap] f32  ->  wt[(c*TAPS+t)*Cout + o]
__global__ __launch_bounds__(256) void k_wxpose(const float* __restrict__ w,
        float* __restrict__ wt, const int Cout, const int CIN, const int TAPS,
        const int n){
  const int i = blockIdx.x*256 + threadIdx.x;
  if (i >= n) return;
  const int ct = CIN*TAPS;
  const int o = i / ct;
  const int rem = i - o*ct;
  const int c = rem / TAPS;
  const int t = rem - c*TAPS;
  wt[((size_t)c*TAPS + t)*Cout + o] = w[i];
}

// ------------------------------------------- XCD-aware block decode ------
template<int GY>
__device__ __forceinline__ bool blk_decode(int& xs, int& yg){
  const int id  = blockIdx.x;
  const int xcd = id & 7;
  const int s   = id >> 3;
  yg = s & (GY-1);
  const int k = s / GY;
  xs = xcd*TPX + k;
  return xs < PXT;
}

// pair-pixel decode: lane -> 2 adjacent px (x even)
__device__ __forceinline__ void pair_decode(const int xs, int& b, int& r0, int& po){
  const int lane = threadIdx.x & 63;
  const int pb = xs*128;
  b = pb / HW;
  r0 = pb - b*HW + 2*lane;
  const int y = r0 / WW, x = r0 - y*WW;
  po = POFF(y,x);
}

// ------------------------------------------------ e1: 7x7, 16ch, f64 in --
// bit-identical to r9's e1 path (tap outer, single 16-ch f32 chunk)
__global__ __launch_bounds__(256) void k_e1(const double* __restrict__ cdp,
        const float* __restrict__ wt, const float* __restrict__ bias,
        float* __restrict__ out){
  const int NACC = 8;
  int xs, yg;
  if (!blk_decode<4>(xs, yg)) return;
  const int wvu = __builtin_amdgcn_readfirstlane((int)(threadIdx.x >> 6));
  const int ow0 = (yg*4 + wvu)*NACC;
  int b, r0, po;
  pair_decode(xs, b, r0, po);
  double acc[2][NACC];
  #pragma unroll
  for (int j=0;j<NACC;++j){
    const double bj = (double)bias[ow0+j];
    acc[0][j]=bj; acc[1][j]=bj;
  }
  const double* inb = cdp + (size_t)b*16*PHW;
  #pragma unroll 1
  for (int t=0;t<49;++t){
    const int pot = po + (t/7 - 3)*PWW + (t%7 - 3);
    float ca[2][NACC];
    #pragma unroll
    for (int j=0;j<NACC;++j){ ca[0][j]=0.f; ca[1][j]=0.f; }
    const float* wr = wt + (size_t)t*HD + ow0;
    #pragma unroll 4
    for (int c=0;c<16;++c){
      const double* p = inb + (size_t)c*PHW + pot;
      const float v0 = (float)p[0];
      const float v1 = (float)p[1];
      #pragma unroll
      for (int j=0;j<NACC;++j){
        const float wj = wr[j];
        ca[0][j] = fmaf(v0, wj, ca[0][j]);
        ca[1][j] = fmaf(v1, wj, ca[1][j]);
      }
      wr += (size_t)49*HD;
    }
    #pragma unroll
    for (int j=0;j<NACC;++j){ acc[0][j]+=(double)ca[0][j]; acc[1][j]+=(double)ca[1][j]; }
  }
  #pragma unroll
  for (int j=0;j<NACC;++j){
    double v0 = acc[0][j]; v0 = v0>0.0?v0:0.0;
    double v1 = acc[1][j]; v1 = v1>0.0?v1:0.0;
    stf2(out + ((size_t)b*HD + ow0 + j)*PHW + po, (float)v0, (float)v1);
  }
}

// ------------------------------------------------ 3x3 conv, 128ch, f32 ---
// r9 fconv order: tap OUTER, chunk-32 inner, unconditional halo loads.
template<int NACC,int GY,int ACT>
__global__ __launch_bounds__(256) void k_fc3(const float* __restrict__ in,
        const float* __restrict__ wt, const float* __restrict__ bias,
        float* __restrict__ out, const int Cout){
  int xs, yg;
  if (!blk_decode<GY>(xs, yg)) return;
  const int wvu = __builtin_amdgcn_readfirstlane((int)(threadIdx.x >> 6));
  const int ow0 = (yg*4 + wvu)*NACC;
  int b, r0, po;
  pair_decode(xs, b, r0, po);
  double acc[2][NACC];
  #pragma unroll
  for (int j=0;j<NACC;++j){
    const double bj = (double)bias[ow0+j];
    acc[0][j]=bj; acc[1][j]=bj;
  }
  const float* inb = in + (size_t)b*128*PHW;
  #pragma unroll 1
  for (int t=0;t<9;++t){
    const int pot = po + (t/3 - 1)*PWW + (t%3 - 1);
    #pragma unroll 1
    for (int c0=0;c0<128;c0+=32){
      float ca[2][NACC];
      #pragma unroll
      for (int j=0;j<NACC;++j){ ca[0][j]=0.f; ca[1][j]=0.f; }
      const float* wr = wt + ((size_t)c0*9 + t)*Cout + ow0;
      #pragma unroll 8
      for (int c=0;c<32;++c){
        const float* p = inb + (size_t)(c0+c)*PHW + pot;
        const float v0 = p[0], v1 = p[1];
        #pragma unroll
        for (int j=0;j<NACC;++j){
          const float wj = wr[j];
          ca[0][j] = fmaf(v0, wj, ca[0][j]);
          ca[1][j] = fmaf(v1, wj, ca[1][j]);
        }
        wr += (size_t)9*Cout;
      }
      #pragma unroll
      for (int j=0;j<NACC;++j){ acc[0][j]+=(double)ca[0][j]; acc[1][j]+=(double)ca[1][j]; }
    }
  }
  #pragma unroll
  for (int j=0;j<NACC;++j){
    double v0 = acc[0][j], v1 = acc[1][j];
    if (ACT==1){ v0 = v0>0.0?v0:0.0; v1 = v1>0.0?v1:0.0; }
    stf2(out + ((size_t)b*Cout + ow0 + j)*PHW + po, (float)v0, (float)v1);
  }
}

// ------------------------------------------- GRU segments (r9 order) -----
// Two-gate (z,r); chunk-32 f32; unconditional halo loads; unroll 4.
template<int C,int NACC>
__device__ __forceinline__ void seg2(const float* __restrict__ plane, const int pot,
    const float* __restrict__ wz0, const float* __restrict__ wr0,
    double az[2][NACC], double ar[2][NACC]){
  #pragma unroll 1
  for (int c0=0;c0<C;c0+=32){
    float cz[2][NACC], cr[2][NACC];
    #pragma unroll
    for (int j=0;j<NACC;++j){ cz[0][j]=0.f; cz[1][j]=0.f; cr[0][j]=0.f; cr[1][j]=0.f; }
    const float* wz = wz0 + (size_t)c0*5*HD;
    const float* wr = wr0 + (size_t)c0*5*HD;
    #pragma unroll 4
    for (int c=0;c<32;++c){
      const float* p = plane + (size_t)(c0+c)*PHW + pot;
      const float v0 = p[0], v1 = p[1];
      #pragma unroll
      for (int j=0;j<NACC;++j){
        const float wzj = wz[j], wrj = wr[j];
        cz[0][j]=fmaf(v0,wzj,cz[0][j]); cz[1][j]=fmaf(v1,wzj,cz[1][j]);
        cr[0][j]=fmaf(v0,wrj,cr[0][j]); cr[1][j]=fmaf(v1,wrj,cr[1][j]);
      }
      wz += 5*HD; wr += 5*HD;
    }
    #pragma unroll
    for (int j=0;j<NACC;++j){
      az[0][j]+=(double)cz[0][j]; az[1][j]+=(double)cz[1][j];
      ar[0][j]+=(double)cr[0][j]; ar[1][j]+=(double)cr[1][j];
    }
  }
}
// Three-gate (z,r,qx).
template<int C,int NACC>
__device__ __forceinline__ void seg3(const float* __restrict__ plane, const int pot,
    const float* __restrict__ wz0, const float* __restrict__ wr0,
    const float* __restrict__ wq0,
    double az[2][NACC], double ar[2][NACC], double aq[2][NACC]){
  #pragma unroll 1
  for (int c0=0;c0<C;c0+=32){
    float cz[2][NACC], cr[2][NACC], cq[2][NACC];
    #pragma unroll
    for (int j=0;j<NACC;++j){
      cz[0][j]=0.f; cz[1][j]=0.f; cr[0][j]=0.f; cr[1][j]=0.f; cq[0][j]=0.f; cq[1][j]=0.f;
    }
    const float* wz = wz0 + (size_t)c0*5*HD;
    const float* wr = wr0 + (size_t)c0*5*HD;
    const float* wq = wq0 + (size_t)c0*5*HD;
    #pragma unroll 4
    for (int c=0;c<32;++c){
      const float* p = plane + (size_t)(c0+c)*PHW + pot;
      const float v0 = p[0], v1 = p[1];
      #pragma unroll
      for (int j=0;j<NACC;++j){
        const float wzj = wz[j], wrj = wr[j], wqj = wq[j];
        cz[0][j]=fmaf(v0,wzj,cz[0][j]); cz[1][j]=fmaf(v1,wzj,cz[1][j]);
        cr[0][j]=fmaf(v0,wrj,cr[0][j]); cr[1][j]=fmaf(v1,wrj,cr[1][j]);
        cq[0][j]=fmaf(v0,wqj,cq[0][j]); cq[1][j]=fmaf(v1,wqj,cq[1][j]);
      }
      wz += 5*HD; wr += 5*HD; wq += 5*HD;
    }
    #pragma unroll
    for (int j=0;j<NACC;++j){
      az[0][j]+=(double)cz[0][j]; az[1][j]+=(double)cz[1][j];
      ar[0][j]+=(double)cr[0][j]; ar[1][j]+=(double)cr[1][j];
      aq[0][j]+=(double)cq[0][j]; aq[1][j]+=(double)cq[1][j];
    }
  }
}
// One-gate (qh); unroll 8.
template<int C,int NACC>
__device__ __forceinline__ void seg1(const float* __restrict__ plane, const int pot,
    const float* __restrict__ wq0, double aq[2][NACC]){
  #pragma unroll 1
  for (int c0=0;c0<C;c0+=32){
    float cq[2][NACC];
    #pragma unroll
    for (int j=0;j<NACC;++j){ cq[0][j]=0.f; cq[1][j]=0.f; }
    const float* wq = wq0 + (size_t)c0*5*HD;
    #pragma unroll 8
    for (int c=0;c<32;++c){
      const float* p = plane + (size_t)(c0+c)*PHW + pot;
      const float v0 = p[0], v1 = p[1];
      #pragma unroll
      for (int j=0;j<NACC;++j){
        const float wj = wq[j];
        cq[0][j]=fmaf(v0,wj,cq[0][j]); cq[1][j]=fmaf(v1,wj,cq[1][j]);
      }
      wq += 5*HD;
    }
    #pragma unroll
    for (int j=0;j<NACC;++j){ aq[0][j]+=(double)cq[0][j]; aq[1][j]+=(double)cq[1][j]; }
  }
}

// Fused z,r,qx. NACC=4, GY=8. Tap OUTER (r9 order).
template<int VERT>
__global__ __launch_bounds__(256) void k_zrx(
    const float* __restrict__ h, const float* __restrict__ d4,
    const float* __restrict__ ctxp,
    const float* __restrict__ wtz, const float* __restrict__ wtr,
    const float* __restrict__ wtq,
    const float* __restrict__ bz, const float* __restrict__ br,
    const float* __restrict__ bq,
    float* __restrict__ zg, float* __restrict__ rgh, float* __restrict__ qx){
  const int NACC = 4;
  int xs, yg;
  if (!blk_decode<8>(xs, yg)) return;
  const int wvu = __builtin_amdgcn_readfirstlane((int)(threadIdx.x >> 6));
  const int ow0 = (yg*4 + wvu)*NACC;          // 0..124
  int b, r0, po;
  pair_decode(xs, b, r0, po);
  double az[2][NACC], ar[2][NACC], aq[2][NACC];
  #pragma unroll
  for (int j=0;j<NACC;++j){
    const double bzj=(double)bz[ow0+j], brj=(double)br[ow0+j], bqj=(double)bq[ow0+j];
    az[0][j]=bzj; az[1][j]=bzj; ar[0][j]=brj; ar[1][j]=brj; aq[0][j]=bqj; aq[1][j]=bqj;
  }
  const float* hb = h   + (size_t)b*HD *PHW;
  const float* db = d4  + (size_t)b*OCH*PHW;
  const float* cb = ctxp+ (size_t)b*CDC*PHW;
  #pragma unroll 1
  for (int t=0;t<5;++t){
    const int pot = po + (VERT ? (t-2)*PWW : (t-2));
    seg2<HD ,NACC>(hb, pot, wtz + (size_t)t*HD + ow0,
                            wtr + (size_t)t*HD + ow0, az, ar);
    seg3<OCH,NACC>(db, pot, wtz + ((size_t)HD*5 + t)*HD + ow0,
                            wtr + ((size_t)HD*5 + t)*HD + ow0,
                            wtq + ((size_t)HD*5 + t)*HD + ow0, az, ar, aq);
    seg3<CDC,NACC>(cb, pot, wtz + ((size_t)(HD+OCH)*5 + t)*HD + ow0,
                            wtr + ((size_t)(HD+OCH)*5 + t)*HD + ow0,
                            wtq + ((size_t)(HD+OCH)*5 + t)*HD + ow0, az, ar, aq);
  }
  #pragma unroll
  for (int j=0;j<NACC;++j){
    const size_t pp = ((size_t)b*HD + ow0 + j)*PHW + po;
    const float2 hv = ldf2(h + pp);
    const double z0 = 1.0/(1.0+exp(-az[0][j])), z1 = 1.0/(1.0+exp(-az[1][j]));
    const double g0 = (1.0/(1.0+exp(-ar[0][j]))) * (double)hv.x;
    const double g1 = (1.0/(1.0+exp(-ar[1][j]))) * (double)hv.y;
    stf2(zg  + pp, (float)z0, (float)z1);
    stf2(rgh + pp, (float)g0, (float)g1);
    stf2(qx + ((size_t)b*HD + ow0 + j)*HW + r0, (float)aq[0][j], (float)aq[1][j]);
  }
}

// q over rgh (128 ch) + hidden update. NACC=8, GY=4. Tap OUTER.
template<int VERT>
__global__ __launch_bounds__(256) void k_qh(
    const float* __restrict__ rgh, const float* __restrict__ wtq,
    const float* __restrict__ qx, const float* __restrict__ zg,
    float* __restrict__ h){
  const int NACC = 8;
  int xs, yg;
  if (!blk_decode<4>(xs, yg)) return;
  const int wvu = __builtin_amdgcn_readfirstlane((int)(threadIdx.x >> 6));
  const int ow0 = (yg*4 + wvu)*NACC;
  int b, r0, po;
  pair_decode(xs, b, r0, po);
  double aq[2][NACC];
  #pragma unroll
  for (int j=0;j<NACC;++j){
    const float2 q0 = ldf2(qx + ((size_t)b*HD + ow0 + j)*HW + r0);
    aq[0][j] = (double)q0.x; aq[1][j] = (double)q0.y;
  }
  const float* gb = rgh + (size_t)b*HD*PHW;
  #pragma unroll 1
  for (int t=0;t<5;++t){
    const int pot = po + (VERT ? (t-2)*PWW : (t-2));
    seg1<HD,NACC>(gb, pot, wtq + (size_t)t*HD + ow0, aq);
  }
  #pragma unroll
  for (int j=0;j<NACC;++j){
    const size_t pp = ((size_t)b*HD + ow0 + j)*PHW + po;
    const float2 zv = ldf2(zg + pp);
    const float2 hv = ldf2(h  + pp);
    const double z0=(double)zv.x, z1=(double)zv.y;
    const double n0 = (1.0-z0)*(double)hv.x + z0*tanh(aq[0][j]);
    const double n1 = (1.0-z1)*(double)hv.y + z1*tanh(aq[1][j]);
    stf2(h + pp, (float)n0, (float)n1);
  }
}

// ------------------- softmax + depth_r + unc + label + cs + bin update ----
__global__ __launch_bounds__(256) void k_stats(const float* __restrict__ lg,
    double* __restrict__ edges, double* __restrict__ cdp, float* __restrict__ out,
    const int it){
  const int px = blockIdx.x*256 + threadIdx.x;
  const int b = px / HW, r = px - b*HW;
  const int y = r / WW, x = r - y*WW;
  const int pr = POFF(y,x);
  double l[BN], p[BN], c[BN];
  double m = -1e300;
  #pragma unroll
  for (int k=0;k<BN;++k){ l[k] = (double)lg[((size_t)b*BN+k)*PHW + pr]; m = l[k]>m?l[k]:m; }
  double s = 0.0;
  #pragma unroll
  for (int k=0;k<BN;++k){ p[k] = exp(l[k]-m); s += p[k]; }
  double dr = 0.0;
  #pragma unroll
  for (int k=0;k<BN;++k){ c[k] = cdp[((size_t)b*BN+k)*PHW + pr]; p[k] = p[k]/s; dr += p[k]*c[k]; }
  double var = 0.0;
  #pragma unroll
  for (int k=0;k<BN;++k){ const double d = c[k]-dr; var += p[k]*(d*d); }
  const double un = sqrt(var);
  int cnt = 0;
  #pragma unroll
  for (int k=1;k<BN;++k) cnt += (dr >= edges[(b*(BN+1)+k)*HW + r]) ? 1 : 0;
  const double etop = edges[(b*(BN+1)+BN)*HW + r];
  const int label = (dr >= etop) ? 0 : cnt;
  double csv = c[0];
  #pragma unroll
  for (int k=1;k<BN;++k) csv = (label==k) ? c[k] : csv;
  out[((0*6+it)*NB + b)*HW + r] = (float)dr;
  out[((1*6+it)*NB + b)*HW + r] = (float)csv;
  out[((2*6+it)*NB + b)*HW + r] = (float)un;
  const double start = dr - 0.5*un > 0.0 ? dr - 0.5*un : 0.0;
  const double step = un * (1.0/BN);
  double e = start;
  double prev = e < 0.0 ? 0.0 : (e > 80.0 ? 80.0 : e);
  edges[(b*(BN+1)+0)*HW + r] = prev;
  #pragma unroll
  for (int k=1;k<=BN;++k){
    e = e + step;
    const double ec = e < 0.0 ? 0.0 : (e > 80.0 ? 80.0 : e);
    edges[(b*(BN+1)+k)*HW + r] = ec;
    cdp[((size_t)b*BN + (k-1))*PHW + pr] = 0.5*(prev + ec);
    prev = ec;
  }
}

// ----------------------------------------------------------- launcher ----
extern "C" void kernel_launch(void* const* d_in, const int* in_sizes, int n_in,
                              void* d_out, int out_size, void* d_ws, size_t ws_size,
                              hipStream_t stream){
  const float* ctx = (const float*)d_in[1];
  const float* gh  = (const float*)d_in[2];
  const float *e1w=(const float*)d_in[3],  *e1b=(const float*)d_in[4];
  const float *e2w=(const float*)d_in[5],  *e2b=(const float*)d_in[6];
  const float *e3w=(const float*)d_in[7],  *e3b=(const float*)d_in[8];
  const float *e4w=(const float*)d_in[9],  *e4b=(const float*)d_in[10];
  const float *z1w=(const float*)d_in[11], *z1b=(const float*)d_in[12];
  const float *r1w=(const float*)d_in[13], *r1b=(const float*)d_in[14];
  const float *q1w=(const float*)d_in[15], *q1b=(const float*)d_in[16];
  const float *z2w=(const float*)d_in[17], *z2b=(const float*)d_in[18];
  const float *r2w=(const float*)d_in[19], *r2b=(const float*)d_in[20];
  const float *q2w=(const float*)d_in[21], *q2b=(const float*)d_in[22];
  const float *p1w=(const float*)d_in[23], *p1b=(const float*)d_in[24];
  const float *p2w=(const float*)d_in[25], *p2b=(const float*)d_in[26];
  float* out = (float*)d_out;

  // f64 region: edges (unpadded), cdp (padded)
  double* edges = (double*)d_ws;                        // NB*17*HW
  double* cdp   = edges + (size_t)NB*(BN+1)*HW;         // NB*16*PHW
  // f32 padded planes (halo pre-zeroed each launch), then unpadded + weights
  float* fb    = (float*)(cdp + (size_t)NB*BN*PHW);
  float* hp    = fb;                                    // NB*128*PHW
  float* d4p   = hp    + (size_t)NB*HD *PHW;            // NB*256*PHW
  float* bufAp = d4p   + (size_t)NB*OCH*PHW;            // NB*128*PHW
  float* bufBp = bufAp + (size_t)NB*HD *PHW;            // NB*128*PHW
  float* ctxp  = bufBp + (size_t)NB*HD *PHW;            // NB*192*PHW
  float* lgtsp = ctxp  + (size_t)NB*CDC*PHW;            // NB*16*PHW
  const size_t npad32 = (size_t)NB*(HD+OCH+HD+HD+CDC+BN)*PHW;
  float* qx   = lgtsp + (size_t)NB*BN*PHW;              // NB*128*HW (unpadded)
  float* wp   = qx + (size_t)NB*HD*HW;
  float* we1 = wp;              wp += (size_t)HD*16*49;
  float* we2 = wp;              wp += (size_t)HD*HD*9;
  float* we3 = wp;              wp += (size_t)HD*HD*9;
  float* we4 = wp;              wp += (size_t)OCH*HD*9;
  float* wz1 = wp;              wp += (size_t)HD*GC*5;
  float* wr1 = wp;              wp += (size_t)HD*GC*5;
  float* wq1 = wp;              wp += (size_t)HD*GC*5;
  float* wz2 = wp;              wp += (size_t)HD*GC*5;
  float* wr2 = wp;              wp += (size_t)HD*GC*5;
  float* wq2 = wp;              wp += (size_t)HD*GC*5;
  float* wp1 = wp;              wp += (size_t)HD*HD*9;
  float* wp2 = wp;              wp += (size_t)16*HD*9;

  const dim3 blk(256);

  k_zero32<<<dim3(2048), blk, 0, stream>>>(fb, npad32);
  k_zero64<<<dim3(1024), blk, 0, stream>>>(cdp, (size_t)NB*BN*PHW);

  #define XP(src,dst,Cout_,CIN_,TAPS_) { const int n=(Cout_)*(CIN_)*(TAPS_); \
    k_wxpose<<<dim3((n+255)/256), blk, 0, stream>>>(src, dst, Cout_, CIN_, TAPS_, n); }
  XP(e1w, we1, HD, 16, 49); XP(e2w, we2, HD, HD, 9); XP(e3w, we3, HD, HD, 9);
  XP(e4w, we4, OCH, HD, 9);
  XP(z1w, wz1, HD, GC, 5); XP(r1w, wr1, HD, GC, 5); XP(q1w, wq1, HD, GC, 5);
  XP(z2w, wz2, HD, GC, 5); XP(r2w, wr2, HD, GC, 5); XP(q2w, wq2, HD, GC, 5);
  XP(p1w, wp1, HD, HD, 9); XP(p2w, wp2, 16, HD, 9);
  #undef XP

  k_pad<<<dim3((NB*CDC*HW+255)/256), blk, 0, stream>>>(ctx, ctxp, NB*CDC);
  k_init<<<dim3((NB*HD*HW+255)/256), blk, 0, stream>>>(gh, hp, edges, cdp);

  const int G8 = GXP*8, G4 = GXP*4, G1 = GXP;
  const int PXB = BHW/256;

  for (int it=0; it<6; ++it){
    k_e1        <<<dim3(G4), blk, 0, stream>>>(cdp,   we1, e1b, bufAp);
    k_fc3<8,4,1><<<dim3(G4), blk, 0, stream>>>(bufAp, we2, e2b, bufBp, HD);
    k_fc3<8,4,1><<<dim3(G4), blk, 0, stream>>>(bufBp, we3, e3b, bufAp, HD);
    k_fc3<8,8,1><<<dim3(G8), blk, 0, stream>>>(bufAp, we4, e4b, d4p,  OCH);
    // horizontal GRU
    k_zrx<0><<<dim3(G8), blk, 0, stream>>>(hp, d4p, ctxp, wz1, wr1, wq1,
                                           z1b, r1b, q1b, bufAp, bufBp, qx);
    k_qh <0><<<dim3(G4), blk, 0, stream>>>(bufBp, wq1, qx, bufAp, hp);
    // vertical GRU
    k_zrx<1><<<dim3(G8), blk, 0, stream>>>(hp, d4p, ctxp, wz2, wr2, wq2,
                                           z2b, r2b, q2b, bufAp, bufBp, qx);
    k_qh <1><<<dim3(G4), blk, 0, stream>>>(bufBp, wq2, qx, bufAp, hp);
    // PHead
    k_fc3<8,4,1><<<dim3(G4), blk, 0, stream>>>(hp,    wp1, p1b, bufAp, HD);
    k_fc3<4,1,0><<<dim3(G1), blk, 0, stream>>>(bufAp, wp2, p2b, lgtsp, 16);
    k_stats<<<dim3(PXB), blk, 0, stream>>>(lgtsp, edges, cdp, out, it);
  }
}